// Round 3
// baseline (252.275 us; speedup 1.0000x reference)
//
#include <hip/hip_runtime.h>
#include <hip/hip_bf16.h>

// MultiLoRA forward: out[row,o] = sum_r (sum_i x[row,i]*B[a,r,i]) * A[a,o,r]
// f32 I/O, bf16 MFMA compute. SCALING = 16/16 = 1.
#define RANK   16
#define IN_F   4096
#define OUT_F  4096
#define SEQLEN 2048
#define NROWS  8192
#define AB_ELEMS 524288            // 8*4096*16 = 8*16*4096
#define WSP_QSTRIDE (NROWS * RANK) // 131072 f32 per K-quarter partial

typedef __bf16 bf16x4   __attribute__((ext_vector_type(4)));
typedef __bf16 bf16x8   __attribute__((ext_vector_type(8)));
typedef float  floatx4  __attribute__((ext_vector_type(4)));
typedef float  floatx16 __attribute__((ext_vector_type(16)));

// ---------------------------------------------------------------------------
// Pre-pass: convert A (f32) and B (f32) to bf16 once. 1 M elems total, ~2 us.
// Removes 8 cvts per MFMA from both hot loops and halves A/B cache footprint.
// ---------------------------------------------------------------------------
__global__ __launch_bounds__(256) void
cvt_ab_kernel(const float* __restrict__ A, const float* __restrict__ Bw,
              __bf16* __restrict__ A16, __bf16* __restrict__ B16)
{
    const int idx = (blockIdx.x * 256 + threadIdx.x) * 4;  // 512 blocks
    floatx4 a = *reinterpret_cast<const floatx4*>(A + idx);
    floatx4 b = *reinterpret_cast<const floatx4*>(Bw + idx);
    bf16x4 a4, b4;
#pragma unroll
    for (int i = 0; i < 4; ++i) { a4[i] = (__bf16)a[i]; b4[i] = (__bf16)b[i]; }
    *reinterpret_cast<bf16x4*>(A16 + idx) = a4;
    *reinterpret_cast<bf16x4*>(B16 + idx) = b4;
}

// ---------------------------------------------------------------------------
// Stage 1: f32 partials of Bx. Grid = 512 row-tiles x 4 K-quarters = 2048
// blocks (8 blocks/CU -> 32 waves/CU, 100% occupancy). Each block: 4 waves,
// wave k-chunk = 256 (8 MFMA 16x16x32 steps), LDS-reduce 4 partials, store
// f32 to wsP[q][row][r] (contiguous 1 KB per block).
// A-op (x): lane m=lane&15 row, quad*8 k -> 32B contiguous f32, nontemporal.
// B-op (B16): 16B contiguous bf16. C: col=lane&15 (=r), row=quad*4+reg.
// ---------------------------------------------------------------------------
__global__ __launch_bounds__(256, 8) void
lora_bx_partial(const float* __restrict__ x, const __bf16* __restrict__ B16,
                const int* __restrict__ ids, float* __restrict__ wsP)
{
    const int tile = blockIdx.x >> 2;       // 0..511 (16-row tiles)
    const int q    = blockIdx.x & 3;        // K-quarter
    const int row0 = tile * 16;
    const int adapter = ids[row0 / SEQLEN]; // 16 | 2048: no batch crossing
    const int wave = threadIdx.x >> 6;
    const int lane = threadIdx.x & 63;
    const int m    = lane & 15;
    const int quad = lane >> 4;
    const int k0   = q * 1024 + wave * 256;

    const float*  xp = x + (size_t)(row0 + m) * IN_F + k0 + quad * 8;
    const __bf16* bp = B16 + adapter * (RANK * IN_F) + m * IN_F + k0 + quad * 8;

    floatx4 acc = {0.f, 0.f, 0.f, 0.f};
#pragma unroll
    for (int s = 0; s < 8; ++s) {
        floatx4 xa = __builtin_nontemporal_load(
            reinterpret_cast<const floatx4*>(xp + s * 32));
        floatx4 xb = __builtin_nontemporal_load(
            reinterpret_cast<const floatx4*>(xp + s * 32 + 4));
        bf16x8 bf = *reinterpret_cast<const bf16x8*>(bp + s * 32);
        bf16x8 af;
        af[0] = (__bf16)xa[0]; af[1] = (__bf16)xa[1];
        af[2] = (__bf16)xa[2]; af[3] = (__bf16)xa[3];
        af[4] = (__bf16)xb[0]; af[5] = (__bf16)xb[1];
        af[6] = (__bf16)xb[2]; af[7] = (__bf16)xb[3];
        acc = __builtin_amdgcn_mfma_f32_16x16x32_bf16(af, bf, acc, 0, 0, 0);
    }

    __shared__ float red[4][256];
#pragma unroll
    for (int j = 0; j < 4; ++j)
        red[wave][(quad * 4 + j) * 16 + m] = acc[j];  // [row%16][r]
    __syncthreads();

    const int t = threadIdx.x;  // t = (row%16)*16 + r
    float s = (red[0][t] + red[1][t]) + (red[2][t] + red[3][t]);
    wsP[(size_t)q * WSP_QSTRIDE + tile * 256 + t] = s;  // = q*131072 + row*16 + r
}

// ---------------------------------------------------------------------------
// Stage 2: out = Bx * A^T via mfma_f32_32x32x16_bf16 (K = RANK = 16 exactly).
// Grid = 256 row-tiles x 8 col-chunks = 2048 blocks (8/CU, 100% occupancy);
// each wave: 4 col-tiles of 32. A-operand built once per wave by summing the
// 4 f32 K-partials (L2) then cvt to bf16. Stores nontemporal f32.
// A-op (Bx): lane holds rows m=lane&31, k=half*8+j. B-op (A16): o=lane&31,
// rank-contiguous 16B. C: col=lane&31, row=(reg&3)+8*(reg>>2)+4*half.
// ---------------------------------------------------------------------------
__global__ __launch_bounds__(256, 8) void
lora_out_kernel(const float* __restrict__ wsP, const __bf16* __restrict__ A16,
                const int* __restrict__ ids, float* __restrict__ out)
{
    const int rt    = blockIdx.x >> 3;      // 0..255 (32-row tiles)
    const int chunk = blockIdx.x & 7;       // 512-col chunks
    const int row0  = rt * 32;
    const int adapter = ids[row0 / SEQLEN];
    const int wave = threadIdx.x >> 6;
    const int lane = threadIdx.x & 63;
    const int n    = lane & 31;
    const int half = lane >> 5;

    // Sum the 4 K-quarter partials for this lane's Bx fragment, cvt to bf16.
    const float* pp = wsP + (size_t)(row0 + n) * RANK + half * 8;
    floatx4 s0 = *reinterpret_cast<const floatx4*>(pp);
    floatx4 s1 = *reinterpret_cast<const floatx4*>(pp + 4);
#pragma unroll
    for (int q = 1; q < 4; ++q) {
        s0 += *reinterpret_cast<const floatx4*>(pp + q * WSP_QSTRIDE);
        s1 += *reinterpret_cast<const floatx4*>(pp + q * WSP_QSTRIDE + 4);
    }
    bf16x8 a_bx;
    a_bx[0] = (__bf16)s0[0]; a_bx[1] = (__bf16)s0[1];
    a_bx[2] = (__bf16)s0[2]; a_bx[3] = (__bf16)s0[3];
    a_bx[4] = (__bf16)s1[0]; a_bx[5] = (__bf16)s1[1];
    a_bx[6] = (__bf16)s1[2]; a_bx[7] = (__bf16)s1[3];

    const __bf16* ap = A16 + adapter * (OUT_F * RANK) + half * 8;
    const int colbase = chunk * 512 + wave * 128;

#pragma unroll
    for (int tcol = 0; tcol < 4; ++tcol) {
        const int col0 = colbase + tcol * 32;
        bf16x8 bfrag = *reinterpret_cast<const bf16x8*>(
            ap + (size_t)(col0 + n) * RANK);
        floatx16 c;
#pragma unroll
        for (int i = 0; i < 16; ++i) c[i] = 0.f;
        c = __builtin_amdgcn_mfma_f32_32x32x16_bf16(a_bx, bfrag, c, 0, 0, 0);
#pragma unroll
        for (int reg = 0; reg < 16; ++reg) {
            const int r = (reg & 3) + 8 * (reg >> 2) + 4 * half;
            __builtin_nontemporal_store(
                c[reg], out + (size_t)(row0 + r) * OUT_F + col0 + n);
        }
    }
}

extern "C" void kernel_launch(void* const* d_in, const int* in_sizes, int n_in,
                              void* d_out, int out_size, void* d_ws, size_t ws_size,
                              hipStream_t stream) {
    const float* x   = (const float*)d_in[0]; // [4, 2048, 4096] f32
    const float* Aw  = (const float*)d_in[1]; // [8, 4096, 16]   f32
    const float* Bw  = (const float*)d_in[2]; // [8, 16, 4096]   f32
    const int*   ids = (const int*)d_in[3];   // [4] int32
    float* out = (float*)d_out;               // [4, 2048, 4096] f32

    // ws layout: A16 (1 MB) | B16 (1 MB) | wsP f32 partials (2 MB)
    __bf16* A16 = (__bf16*)d_ws;
    __bf16* B16 = A16 + AB_ELEMS;
    float*  wsP = (float*)(B16 + AB_ELEMS);

    cvt_ab_kernel <<<dim3(AB_ELEMS / 1024), dim3(256), 0, stream>>>(Aw, Bw, A16, B16);
    lora_bx_partial<<<dim3(512 * 4),         dim3(256), 0, stream>>>(x, B16, ids, wsP);
    lora_out_kernel<<<dim3(256 * 8),         dim3(256), 0, stream>>>(wsP, A16, ids, out);
}

// Round 4
// 250.525 us; speedup vs baseline: 1.0070x; 1.0070x over previous
//
#include <hip/hip_runtime.h>
#include <hip/hip_bf16.h>

// MultiLoRA forward, fully fused:
//   out[row,o] = sum_r (sum_i x[row,i]*B[a,r,i]) * A[a,o,r],  a = ids[row/2048]
// f32 I/O, bf16 MFMA compute. SCALING = 16/16 = 1.
// One kernel, one block per 16-row tile (512 blocks x 512 threads = 8 waves).
// Phase 1: waves K-split 4096 8-ways -> 16 MFMA(16x16x32) each -> LDS reduce
//          -> Bx tile [16 rows x 16 r] as bf16 in LDS.
// Phase 2: mfma_f32_32x32x16_bf16 with K=RANK=16 exactly; A-operand rows
//          16..31 duplicate rows 0..15 (only regs 0..7 = rows 0..15 stored).
#define RANK   16
#define IN_F   4096
#define OUT_F  4096
#define SEQLEN 2048
#define NROWS  8192

typedef __bf16 bf16x8   __attribute__((ext_vector_type(8)));
typedef float  floatx4  __attribute__((ext_vector_type(4)));
typedef float  floatx16 __attribute__((ext_vector_type(16)));

static __device__ __forceinline__ bf16x8 cvt8(floatx4 a, floatx4 b) {
    bf16x8 r;
    r[0] = (__bf16)a[0]; r[1] = (__bf16)a[1]; r[2] = (__bf16)a[2]; r[3] = (__bf16)a[3];
    r[4] = (__bf16)b[0]; r[5] = (__bf16)b[1]; r[6] = (__bf16)b[2]; r[7] = (__bf16)b[3];
    return r;
}

__global__ __launch_bounds__(512, 4) void
lora_fused_kernel(const float* __restrict__ x, const float* __restrict__ Aw,
                  const float* __restrict__ Bw, const int* __restrict__ ids,
                  float* __restrict__ out)
{
    const int tile = blockIdx.x;            // 0..511, 16-row tiles
    const int row0 = tile * 16;
    const int adapter = ids[row0 >> 11];    // 16 | 2048: no batch crossing
    const int tid  = threadIdx.x;
    const int wave = tid >> 6;              // 0..7
    const int lane = tid & 63;

    __shared__ float  red[8][256];          // per-wave C-tile partials
    __shared__ __bf16 bxs[256];             // Bx tile [row%16][r], bf16

    // ---- Phase 1: Bx[row, r] = sum_i x[row,i] * B[a,r,i], K-split 8 ways ----
    {
        const int m    = lane & 15;         // x row (and C col = r via lane)
        const int quad = lane >> 4;
        const int k0   = wave * 512 + quad * 8;
        const float* xp = x + (size_t)(row0 + m) * IN_F + k0;
        const float* bp = Bw + (size_t)adapter * (RANK * IN_F) + m * IN_F + k0;

        floatx4 acc = {0.f, 0.f, 0.f, 0.f};
#pragma unroll
        for (int s = 0; s < 16; ++s) {      // 16 steps of k32
            floatx4 xa = *reinterpret_cast<const floatx4*>(xp + s * 32);
            floatx4 xb = *reinterpret_cast<const floatx4*>(xp + s * 32 + 4);
            floatx4 ba = *reinterpret_cast<const floatx4*>(bp + s * 32);
            floatx4 bb = *reinterpret_cast<const floatx4*>(bp + s * 32 + 4);
            acc = __builtin_amdgcn_mfma_f32_16x16x32_bf16(
                cvt8(xa, xb), cvt8(ba, bb), acc, 0, 0, 0);
        }
        // C layout: row = quad*4 + j (x-row), col = lane&15 (= r)
#pragma unroll
        for (int j = 0; j < 4; ++j)
            red[wave][(quad * 4 + j) * 16 + m] = acc[j];
    }
    __syncthreads();
    if (tid < 256) {                        // t = (row%16)*16 + r
        float s = ((red[0][tid] + red[1][tid]) + (red[2][tid] + red[3][tid]))
                + ((red[4][tid] + red[5][tid]) + (red[6][tid] + red[7][tid]));
        bxs[tid] = (__bf16)s;
    }
    __syncthreads();

    // ---- Phase 2: out[row, o] = sum_r Bx[row,r] * A[a,o,r] ----
    {
        const int n    = lane & 31;         // out col within tile
        const int half = lane >> 5;         // k half: k = half*8 + j
        const int mm   = n & 15;            // A-op row; rows 16..31 duplicate

        const bf16x8 a_bx = *reinterpret_cast<const bf16x8*>(bxs + mm * 16 + half * 8);
        const float* ap = Aw + (size_t)adapter * (OUT_F * RANK) + half * 8;

#pragma unroll 4
        for (int t = 0; t < 16; ++t) {      // 8 waves x 16 tiles x 32 = 4096 cols
            const int col0 = (wave * 16 + t) * 32;
            floatx4 fa = *reinterpret_cast<const floatx4*>(ap + (size_t)(col0 + n) * RANK);
            floatx4 fb = *reinterpret_cast<const floatx4*>(ap + (size_t)(col0 + n) * RANK + 4);
            floatx16 c;
#pragma unroll
            for (int i = 0; i < 16; ++i) c[i] = 0.f;
            c = __builtin_amdgcn_mfma_f32_32x32x16_bf16(a_bx, cvt8(fa, fb), c, 0, 0, 0);
            // C layout: col = lane&31, row = (reg&3) + 8*(reg>>2) + 4*half.
            // regs 0..7 -> rows 0..15 (valid); regs 8..15 duplicate -> skip.
#pragma unroll
            for (int reg = 0; reg < 8; ++reg) {
                const int r = (reg & 3) + 8 * (reg >> 2) + 4 * half;
                __builtin_nontemporal_store(
                    c[reg], out + (size_t)(row0 + r) * OUT_F + col0 + n);
            }
        }
    }
}

extern "C" void kernel_launch(void* const* d_in, const int* in_sizes, int n_in,
                              void* d_out, int out_size, void* d_ws, size_t ws_size,
                              hipStream_t stream) {
    const float* x   = (const float*)d_in[0]; // [4, 2048, 4096] f32
    const float* Aw  = (const float*)d_in[1]; // [8, 4096, 16]   f32
    const float* Bw  = (const float*)d_in[2]; // [8, 16, 4096]   f32
    const int*   ids = (const int*)d_in[3];   // [4] int32
    float* out = (float*)d_out;               // [4, 2048, 4096] f32

    lora_fused_kernel<<<dim3(NROWS / 16), dim3(512), 0, stream>>>(x, Aw, Bw, ids, out);
}